// Round 21
// baseline (97.576 us; speedup 1.0000x reference)
//
#include <hip/hip_runtime.h>
#include <math.h>

#define N_NODES 100000
#define N_EDGES 1600000
#define D_IN 64
#define D_HID 128

#define BKT_SHIFT 7
#define BKT_NODES 128
#define NB ((N_NODES + BKT_NODES - 1) / BKT_NODES)  // 782
#define CAP 4096                                     // per-bucket capacity (mean ~2046)
#define CHUNK 8192
#define BIN_T 1024
#define AGG_T 1024

#define GM_T 256
#define GM_NODES 128
#define GM_NBLK ((N_NODES + GM_NODES - 1) / GM_NODES)  // 782

// fixed-point scales for LDS integer accumulation
#define SCALE_L1 1048576.0f          // 2^20
#define INV_SCALE_L1 9.5367431640625e-7f
#define SCALE_L2 2097152.0f          // 2^21
#define INV_SCALE_L2 4.76837158203125e-7f

// packed edge: bits 0..16 = row (src node), bits 17..23 = dst & 127
#define PACK(row, col) (((unsigned)((col) & (BKT_NODES - 1)) << 17) | (unsigned)(row))
#define P_ROW(u) ((int)((u) & 0x1FFFFu))
#define P_DST(u) ((int)(((u) >> 17) & 0x7Fu))

typedef __attribute__((ext_vector_type(8))) short bf16x8;
typedef __attribute__((ext_vector_type(4))) float f32x4;

static __device__ __forceinline__ unsigned short f2bf(float f) {
    unsigned int u = __float_as_uint(f);
    u += 0x7FFFu + ((u >> 16) & 1u);  // round-to-nearest-even
    return (unsigned short)(u >> 16);
}
static __device__ __forceinline__ float bfu(unsigned short s) {
    return __uint_as_float(((unsigned)s) << 16);
}

// ---------------- phase 1: LDS counting-sort edges into 782 col-buckets ------
// block 0 additionally packs W1 into MFMA B-fragment order (bf16).

__global__ __launch_bounds__(BIN_T) void k_bin(const int* __restrict__ row,
                                               const int* __restrict__ col,
                                               const float* __restrict__ W1,
                                               int* __restrict__ gcur,
                                               unsigned* __restrict__ pairs,
                                               unsigned short* __restrict__ wpack) {
    __shared__ int bcnt[NB];
    __shared__ int boff[NB];
    __shared__ int gbase[NB];
    __shared__ int sc[1024];
    __shared__ unsigned stage[CHUNK];          // 32 KB
    __shared__ unsigned short bkt_of[CHUNK];   // 16 KB
    const int t = threadIdx.x;
    const int e0 = blockIdx.x * CHUNK;
    const int nE = min(CHUNK, N_EDGES - e0);

    for (int i = t; i < NB; i += BIN_T) bcnt[i] = 0;
    __syncthreads();

    int myb[8], myrank[8], myr[8];
#pragma unroll
    for (int k = 0; k < 8; ++k) {
        const int i = t + k * BIN_T;
        if (i < nE) {
            myr[k] = row[e0 + i];
            const int c = col[e0 + i];
            myb[k] = c >> BKT_SHIFT;
            myrank[k] = atomicAdd(&bcnt[myb[k]], 1);
            myr[k] = PACK(myr[k], c);
        }
    }
    __syncthreads();

    sc[t] = (t < NB) ? bcnt[t] : 0;
    __syncthreads();
    for (int off = 1; off < 1024; off <<= 1) {
        int v = (t >= off) ? sc[t - off] : 0;
        __syncthreads();
        sc[t] += v;
        __syncthreads();
    }
    if (t < NB) {
        boff[t] = sc[t] - bcnt[t];
        if (bcnt[t] > 0) gbase[t] = atomicAdd(&gcur[t], bcnt[t]);
    }
    __syncthreads();

    // stage into bucket-sorted order in LDS; record bucket per slot inline
#pragma unroll
    for (int k = 0; k < 8; ++k) {
        const int i = t + k * BIN_T;
        if (i < nE) {
            const int pos = boff[myb[k]] + myrank[k];
            stage[pos] = (unsigned)myr[k];
            bkt_of[pos] = (unsigned short)myb[k];
        }
    }
    __syncthreads();

    for (int s = t; s < nE; s += BIN_T) {
        const int b = bkt_of[s];
        pairs[(size_t)b * CAP + gbase[b] + (s - boff[b])] = stage[s];
    }

    // block 0 tail: pack W1 -> B-fragments for mfma_f32_16x16x32_bf16.
    if (blockIdx.x == 0) {
        for (int idx = t; idx < 8 * 2 * 64 * 8; idx += BIN_T) {
            const int j = idx & 7;
            const int l = (idx >> 3) & 63;
            const int kk = (idx >> 9) & 1;
            const int d = idx >> 10;
            const int krow = (l >> 4) * 8 + kk * 32 + j;
            wpack[idx] = f2bf(W1[krow * D_HID + d * 16 + (l & 15)]);
        }
    }
}

// ---------------- per-bucket degrees -> dinv + xb = bf16(dinv*|x|) -----------

__global__ __launch_bounds__(AGG_T) void k_deg(const unsigned* __restrict__ pairs,
                                               const int* __restrict__ gcur,
                                               const float* __restrict__ x,
                                               float* __restrict__ dinv,
                                               unsigned short* __restrict__ xb) {
    __shared__ int ncnt[BKT_NODES];
    const int b = blockIdx.x, t = threadIdx.x;
    const int base = b << BKT_SHIFT;
    const int nNodes = min(BKT_NODES, N_NODES - base);
    const int nE = gcur[b];
    const unsigned* bp = pairs + (size_t)b * CAP;

    if (t < BKT_NODES) ncnt[t] = 0;
    __syncthreads();
    for (int i = t; i < nE; i += AGG_T) atomicAdd(&ncnt[P_DST(bp[i])], 1);
    __syncthreads();

    if (t < nNodes) dinv[base + t] = rsqrtf((float)ncnt[t] + 1.0f);

    for (int i = t; i < nNodes * 16; i += AGG_T) {
        const int nl = i >> 4;
        const int q = i & 15;
        const float di = rsqrtf((float)ncnt[nl] + 1.0f);
        const float4 v = ((const float4*)(x + (size_t)(base + nl) * D_IN))[q];
        ushort4 o4;
        o4.x = f2bf(di * fabsf(v.x));
        o4.y = f2bf(di * fabsf(v.y));
        o4.z = f2bf(di * fabsf(v.z));
        o4.w = f2bf(di * fabsf(v.w));
        *(ushort4*)(xb + (size_t)(base + nl) * D_IN + q * 4) = o4;
    }
}

// ---------------- layer-1 aggregate: LDS int fixed-point scatter-add ---------
// acc[128][65] int = 33.3 KB -> 2 blocks/CU @ 1024 threads.
// 8 gathers in flight per lane (R20 post-mortem: 4-deep had VGPR=20-24 --
// MLP, not occupancy, was the residual limiter). atomicAdd(int) on LDS =
// native ds_add_u32 (R16-R18 saga: float LDS atomics are CAS loops).

#define ATOM8(dst_, v_)                                                         \
    do {                                                                        \
        int* a_ = acc + (dst_) * 65 + dc * 8;                                   \
        atomicAdd(a_ + 0, (int)(bfu((unsigned short)((v_).x & 0xFFFF)) * SCALE_L1)); \
        atomicAdd(a_ + 1, (int)(bfu((unsigned short)((v_).x >> 16)) * SCALE_L1));    \
        atomicAdd(a_ + 2, (int)(bfu((unsigned short)((v_).y & 0xFFFF)) * SCALE_L1)); \
        atomicAdd(a_ + 3, (int)(bfu((unsigned short)((v_).y >> 16)) * SCALE_L1));    \
        atomicAdd(a_ + 4, (int)(bfu((unsigned short)((v_).z & 0xFFFF)) * SCALE_L1)); \
        atomicAdd(a_ + 5, (int)(bfu((unsigned short)((v_).z >> 16)) * SCALE_L1));    \
        atomicAdd(a_ + 6, (int)(bfu((unsigned short)((v_).w & 0xFFFF)) * SCALE_L1)); \
        atomicAdd(a_ + 7, (int)(bfu((unsigned short)((v_).w >> 16)) * SCALE_L1));    \
    } while (0)

__global__ __launch_bounds__(AGG_T) void k_aggL1(const unsigned* __restrict__ pairs,
                                                 const int* __restrict__ gcur,
                                                 const unsigned short* __restrict__ xb,
                                                 unsigned short* __restrict__ aggb) {
    __shared__ int acc[BKT_NODES * 65];  // 33.28 KB
    const int b = blockIdx.x, t = threadIdx.x;
    const int base = b << BKT_SHIFT;
    const int nNodes = min(BKT_NODES, N_NODES - base);
    const int nE = gcur[b];
    const unsigned* bp = pairs + (size_t)b * CAP;

    for (int i = t; i < BKT_NODES * 65; i += AGG_T) acc[i] = 0;
    __syncthreads();

    const int slot = t >> 3;   // 0..127 edge slots
    const int dc = t & 7;      // dims 8*dc..8*dc+7
    int i = slot;
    for (; i + 896 < nE; i += 1024) {  // 8 gathers in flight per lane
        const unsigned u0 = bp[i];
        const unsigned u1 = bp[i + 128];
        const unsigned u2 = bp[i + 256];
        const unsigned u3 = bp[i + 384];
        const unsigned u4 = bp[i + 512];
        const unsigned u5 = bp[i + 640];
        const unsigned u6 = bp[i + 768];
        const unsigned u7 = bp[i + 896];
        const uint4 v0 = ((const uint4*)(xb + (size_t)P_ROW(u0) * D_IN))[dc];
        const uint4 v1 = ((const uint4*)(xb + (size_t)P_ROW(u1) * D_IN))[dc];
        const uint4 v2 = ((const uint4*)(xb + (size_t)P_ROW(u2) * D_IN))[dc];
        const uint4 v3 = ((const uint4*)(xb + (size_t)P_ROW(u3) * D_IN))[dc];
        const uint4 v4 = ((const uint4*)(xb + (size_t)P_ROW(u4) * D_IN))[dc];
        const uint4 v5 = ((const uint4*)(xb + (size_t)P_ROW(u5) * D_IN))[dc];
        const uint4 v6 = ((const uint4*)(xb + (size_t)P_ROW(u6) * D_IN))[dc];
        const uint4 v7 = ((const uint4*)(xb + (size_t)P_ROW(u7) * D_IN))[dc];
        ATOM8(P_DST(u0), v0);
        ATOM8(P_DST(u1), v1);
        ATOM8(P_DST(u2), v2);
        ATOM8(P_DST(u3), v3);
        ATOM8(P_DST(u4), v4);
        ATOM8(P_DST(u5), v5);
        ATOM8(P_DST(u6), v6);
        ATOM8(P_DST(u7), v7);
    }
    for (; i < nE; i += 128) {
        const unsigned u = bp[i];
        const uint4 v = ((const uint4*)(xb + (size_t)P_ROW(u) * D_IN))[dc];
        ATOM8(P_DST(u), v);
    }
    __syncthreads();

    // add self-loop (float) and pack to bf16 aggb; thread covers 16 dims
    for (int j = t; j < nNodes * 4; j += AGG_T) {
        const int nl = j >> 2;
        const int q = j & 3;          // dims q*16 .. q*16+15
        const uint4 s0 = ((const uint4*)(xb + (size_t)(base + nl) * D_IN))[q * 2];
        const uint4 s1 = ((const uint4*)(xb + (size_t)(base + nl) * D_IN))[q * 2 + 1];
        const int* ar = acc + nl * 65 + q * 16;
        uint4 w0, w1;
        w0.x = (unsigned)f2bf((float)ar[0] * INV_SCALE_L1 + bfu((unsigned short)(s0.x & 0xFFFF))) |
               ((unsigned)f2bf((float)ar[1] * INV_SCALE_L1 + bfu((unsigned short)(s0.x >> 16))) << 16);
        w0.y = (unsigned)f2bf((float)ar[2] * INV_SCALE_L1 + bfu((unsigned short)(s0.y & 0xFFFF))) |
               ((unsigned)f2bf((float)ar[3] * INV_SCALE_L1 + bfu((unsigned short)(s0.y >> 16))) << 16);
        w0.z = (unsigned)f2bf((float)ar[4] * INV_SCALE_L1 + bfu((unsigned short)(s0.z & 0xFFFF))) |
               ((unsigned)f2bf((float)ar[5] * INV_SCALE_L1 + bfu((unsigned short)(s0.z >> 16))) << 16);
        w0.w = (unsigned)f2bf((float)ar[6] * INV_SCALE_L1 + bfu((unsigned short)(s0.w & 0xFFFF))) |
               ((unsigned)f2bf((float)ar[7] * INV_SCALE_L1 + bfu((unsigned short)(s0.w >> 16))) << 16);
        w1.x = (unsigned)f2bf((float)ar[8] * INV_SCALE_L1 + bfu((unsigned short)(s1.x & 0xFFFF))) |
               ((unsigned)f2bf((float)ar[9] * INV_SCALE_L1 + bfu((unsigned short)(s1.x >> 16))) << 16);
        w1.y = (unsigned)f2bf((float)ar[10] * INV_SCALE_L1 + bfu((unsigned short)(s1.y & 0xFFFF))) |
               ((unsigned)f2bf((float)ar[11] * INV_SCALE_L1 + bfu((unsigned short)(s1.y >> 16))) << 16);
        w1.z = (unsigned)f2bf((float)ar[12] * INV_SCALE_L1 + bfu((unsigned short)(s1.z & 0xFFFF))) |
               ((unsigned)f2bf((float)ar[13] * INV_SCALE_L1 + bfu((unsigned short)(s1.z >> 16))) << 16);
        w1.w = (unsigned)f2bf((float)ar[14] * INV_SCALE_L1 + bfu((unsigned short)(s1.w & 0xFFFF))) |
               ((unsigned)f2bf((float)ar[15] * INV_SCALE_L1 + bfu((unsigned short)(s1.w >> 16))) << 16);
        uint4* dst = (uint4*)(aggb + (size_t)(base + nl) * D_IN + q * 16);
        dst[0] = w0;
        dst[1] = w1;
    }
}

// ---------------- MFMA GEMM: g = aggb @ W1; h=relu(di*g+b1); z=di*(h.W2) ----

#define EPI(di_, accv, reg, p_)                                            \
    do {                                                                   \
        float h_ = fmaxf(fmaf((di_), (accv)[reg], b1v), 0.0f);             \
        (p_) = fmaf(h_, w2v, (p_));                                        \
    } while (0)

#define RSTORE(p_, di_, nn_)                                               \
    do {                                                                   \
        float sv = (p_);                                                   \
        sv += __shfl_xor(sv, 1, 64);                                       \
        sv += __shfl_xor(sv, 2, 64);                                       \
        sv += __shfl_xor(sv, 4, 64);                                       \
        sv += __shfl_xor(sv, 8, 64);                                       \
        if ((lane & 15) == 0 && (nn_) < N_NODES) z[(nn_)] = (di_) * sv;    \
    } while (0)

__global__ __launch_bounds__(GM_T) void k_gemm(const unsigned short* __restrict__ aggb,
                                               const unsigned short* __restrict__ wpack,
                                               const float* __restrict__ dinv,
                                               const float* __restrict__ b1,
                                               const float* __restrict__ W2,
                                               float* __restrict__ z) {
    const int t = threadIdx.x;
    const int lane = t & 63;
    const int w = t >> 6;                  // wave 0..3
    const int kg = lane >> 4;              // 0..3
    const int n0 = blockIdx.x * GM_NODES;
    const int nbase0 = n0 + (2 * w) * 16;
    const int nbase1 = nbase0 + 16;

    const bf16x8 a00 = *(const bf16x8*)(aggb + (size_t)(nbase0 + (lane & 15)) * D_IN + kg * 8);
    const bf16x8 a01 = *(const bf16x8*)(aggb + (size_t)(nbase0 + (lane & 15)) * D_IN + kg * 8 + 32);
    const bf16x8 a10 = *(const bf16x8*)(aggb + (size_t)(nbase1 + (lane & 15)) * D_IN + kg * 8);
    const bf16x8 a11 = *(const bf16x8*)(aggb + (size_t)(nbase1 + (lane & 15)) * D_IN + kg * 8 + 32);

    const float di00 = dinv[nbase0 + kg * 4 + 0];
    const float di01 = dinv[nbase0 + kg * 4 + 1];
    const float di02 = dinv[nbase0 + kg * 4 + 2];
    const float di03 = dinv[nbase0 + kg * 4 + 3];
    const float di10 = dinv[nbase1 + kg * 4 + 0];
    const float di11 = dinv[nbase1 + kg * 4 + 1];
    const float di12 = dinv[nbase1 + kg * 4 + 2];
    const float di13 = dinv[nbase1 + kg * 4 + 3];

    float p00 = 0, p01 = 0, p02 = 0, p03 = 0;
    float p10 = 0, p11 = 0, p12 = 0, p13 = 0;

#pragma unroll
    for (int d = 0; d < 8; ++d) {
        const bf16x8 wb0 = *(const bf16x8*)(wpack + ((size_t)(d * 2 + 0) * 64 + lane) * 8);
        const bf16x8 wb1 = *(const bf16x8*)(wpack + ((size_t)(d * 2 + 1) * 64 + lane) * 8);
        f32x4 acc0 = {0.0f, 0.0f, 0.0f, 0.0f};
        acc0 = __builtin_amdgcn_mfma_f32_16x16x32_bf16(a00, wb0, acc0, 0, 0, 0);
        acc0 = __builtin_amdgcn_mfma_f32_16x16x32_bf16(a01, wb1, acc0, 0, 0, 0);
        f32x4 acc1 = {0.0f, 0.0f, 0.0f, 0.0f};
        acc1 = __builtin_amdgcn_mfma_f32_16x16x32_bf16(a10, wb0, acc1, 0, 0, 0);
        acc1 = __builtin_amdgcn_mfma_f32_16x16x32_bf16(a11, wb1, acc1, 0, 0, 0);

        const int cold = d * 16 + (lane & 15);
        const float b1v = b1[cold];
        const float w2v = W2[cold];
        EPI(di00, acc0, 0, p00);
        EPI(di01, acc0, 1, p01);
        EPI(di02, acc0, 2, p02);
        EPI(di03, acc0, 3, p03);
        EPI(di10, acc1, 0, p10);
        EPI(di11, acc1, 1, p11);
        EPI(di12, acc1, 2, p12);
        EPI(di13, acc1, 3, p13);
    }

    RSTORE(p00, di00, nbase0 + kg * 4 + 0);
    RSTORE(p01, di01, nbase0 + kg * 4 + 1);
    RSTORE(p02, di02, nbase0 + kg * 4 + 2);
    RSTORE(p03, di03, nbase0 + kg * 4 + 3);
    RSTORE(p10, di10, nbase1 + kg * 4 + 0);
    RSTORE(p11, di11, nbase1 + kg * 4 + 1);
    RSTORE(p12, di12, nbase1 + kg * 4 + 2);
    RSTORE(p13, di13, nbase1 + kg * 4 + 3);
}

// ---------------- layer-2 aggregate + final: LDS int scatter-add -------------

__global__ __launch_bounds__(AGG_T) void k_outL2(const unsigned* __restrict__ pairs,
                                                 const int* __restrict__ gcur,
                                                 const float* __restrict__ z,
                                                 const float* __restrict__ dinv,
                                                 const float* __restrict__ b2,
                                                 float* __restrict__ out) {
    __shared__ int acc2[BKT_NODES];
    const int b = blockIdx.x, t = threadIdx.x;
    const int base = b << BKT_SHIFT;
    const int nNodes = min(BKT_NODES, N_NODES - base);
    const int nE = gcur[b];
    const unsigned* bp = pairs + (size_t)b * CAP;

    if (t < BKT_NODES) acc2[t] = 0;
    __syncthreads();

    int i = t;
    for (; i + AGG_T < nE; i += 2 * AGG_T) {  // 2 z-gathers in flight
        const unsigned u0 = bp[i];
        const unsigned u1 = bp[i + AGG_T];
        const float z0 = z[P_ROW(u0)];
        const float z1 = z[P_ROW(u1)];
        atomicAdd(&acc2[P_DST(u0)], (int)(z0 * SCALE_L2));
        atomicAdd(&acc2[P_DST(u1)], (int)(z1 * SCALE_L2));
    }
    if (i < nE) {
        const unsigned u = bp[i];
        atomicAdd(&acc2[P_DST(u)], (int)(z[P_ROW(u)] * SCALE_L2));
    }
    __syncthreads();

    if (t < nNodes) {
        float s = (float)acc2[t] * INV_SCALE_L2 + z[base + t];
        float v = fmaf(dinv[base + t], s, b2[0]);
        v = fmaxf(v, 0.0f);
        out[base + t] = 1.0f / (1.0f + expf(-v));
    }
}

extern "C" void kernel_launch(void* const* d_in, const int* in_sizes, int n_in,
                              void* d_out, int out_size, void* d_ws, size_t ws_size,
                              hipStream_t stream) {
    const float* x  = (const float*)d_in[0];
    const int* ei   = (const int*)d_in[1];
    const float* W1 = (const float*)d_in[2];
    const float* b1 = (const float*)d_in[3];
    const float* W2 = (const float*)d_in[4];
    const float* b2 = (const float*)d_in[5];
    float* out = (float*)d_out;

    const int* row = ei;
    const int* col = ei + N_EDGES;

    // workspace layout
    char* p = (char*)d_ws;
    float* dinv           = (float*)p;          p += sizeof(float) * N_NODES;
    unsigned short* xb    = (unsigned short*)p; p += sizeof(unsigned short) * (size_t)N_NODES * D_IN;
    unsigned short* aggb  = (unsigned short*)p; p += sizeof(unsigned short) * ((size_t)N_NODES + 128) * D_IN;
    float* z              = (float*)p;          p += sizeof(float) * (N_NODES + 128);
    int* gcur             = (int*)p;            p += sizeof(int) * NB;
    p = (char*)(((size_t)p + 15) & ~(size_t)15);
    unsigned short* wpack = (unsigned short*)p; p += sizeof(unsigned short) * 8192;
    p = (char*)(((size_t)p + 15) & ~(size_t)15);
    unsigned* pairs       = (unsigned*)p;       p += sizeof(unsigned) * (size_t)NB * CAP;

    hipMemsetAsync(gcur, 0, sizeof(int) * NB, stream);
    k_bin<<<(N_EDGES + CHUNK - 1) / CHUNK, BIN_T, 0, stream>>>(row, col, W1, gcur, pairs, wpack);
    k_deg<<<NB, AGG_T, 0, stream>>>(pairs, gcur, x, dinv, xb);
    k_aggL1<<<NB, AGG_T, 0, stream>>>(pairs, gcur, xb, aggb);
    k_gemm<<<GM_NBLK, GM_T, 0, stream>>>(aggb, wpack, dinv, b1, W2, z);
    k_outL2<<<NB, AGG_T, 0, stream>>>(pairs, gcur, z, dinv, b2, out);
}

// Round 22
// 87.210 us; speedup vs baseline: 1.1189x; 1.1189x over previous
//
#include <hip/hip_runtime.h>
#include <math.h>

#define N_NODES 100000
#define N_EDGES 1600000
#define D_IN 64
#define D_HID 128

#define BKT_SHIFT 8
#define BKT_NODES 256
#define NB ((N_NODES + BKT_NODES - 1) / BKT_NODES)  // 391
#define CAP 8192                                     // per-bucket capacity (mean ~4092)
#define CHUNK 8192
#define BIN_T 1024
#define AGG_T 1024

#define GM_T 256
#define GM_NODES 128
#define GM_NBLK ((N_NODES + GM_NODES - 1) / GM_NODES)  // 782

// fixed-point scales for LDS integer accumulation
#define SCALE_L1 1048576.0f          // 2^20
#define INV_SCALE_L1 9.5367431640625e-7f
#define SCALE_L2 2097152.0f          // 2^21
#define INV_SCALE_L2 4.76837158203125e-7f

// packed edge: bits 0..16 = row (src node), bits 17..24 = dst & 255
#define PACK(row, col) (((unsigned)((col) & (BKT_NODES - 1)) << 17) | (unsigned)(row))
#define P_ROW(u) ((int)((u) & 0x1FFFFu))
#define P_DST(u) ((int)(((u) >> 17) & 0xFFu))

typedef __attribute__((ext_vector_type(8))) short bf16x8;
typedef __attribute__((ext_vector_type(4))) float f32x4;

static __device__ __forceinline__ unsigned short f2bf(float f) {
    unsigned int u = __float_as_uint(f);
    u += 0x7FFFu + ((u >> 16) & 1u);  // round-to-nearest-even
    return (unsigned short)(u >> 16);
}
static __device__ __forceinline__ float bfu(unsigned short s) {
    return __uint_as_float(((unsigned)s) << 16);
}

// ---------------- phase 1: LDS counting-sort edges into 391 col-buckets ------
// block 0 additionally packs W1 into MFMA B-fragment order (bf16).

__global__ __launch_bounds__(BIN_T) void k_bin(const int* __restrict__ row,
                                               const int* __restrict__ col,
                                               const float* __restrict__ W1,
                                               int* __restrict__ gcur,
                                               unsigned* __restrict__ pairs,
                                               unsigned short* __restrict__ wpack) {
    __shared__ int bcnt[NB];
    __shared__ int boff[NB];
    __shared__ int gbase[NB];
    __shared__ int sc[512];
    __shared__ unsigned stage[CHUNK];          // 32 KB
    __shared__ unsigned short bkt_of[CHUNK];   // 16 KB
    const int t = threadIdx.x;
    const int e0 = blockIdx.x * CHUNK;
    const int nE = min(CHUNK, N_EDGES - e0);

    for (int i = t; i < NB; i += BIN_T) bcnt[i] = 0;
    __syncthreads();

    int myb[8], myrank[8], myr[8];
#pragma unroll
    for (int k = 0; k < 8; ++k) {
        const int i = t + k * BIN_T;
        if (i < nE) {
            myr[k] = row[e0 + i];
            const int c = col[e0 + i];
            myb[k] = c >> BKT_SHIFT;
            myrank[k] = atomicAdd(&bcnt[myb[k]], 1);
            myr[k] = PACK(myr[k], c);
        }
    }
    __syncthreads();

    if (t < 512) sc[t] = (t < NB) ? bcnt[t] : 0;
    __syncthreads();
    for (int off = 1; off < 512; off <<= 1) {
        int v = 0;
        if (t < 512 && t >= off) v = sc[t - off];
        __syncthreads();
        if (t < 512) sc[t] += v;
        __syncthreads();
    }
    if (t < NB) {
        boff[t] = sc[t] - bcnt[t];
        if (bcnt[t] > 0) gbase[t] = atomicAdd(&gcur[t], bcnt[t]);
    }
    __syncthreads();

    // stage into bucket-sorted order in LDS; record bucket per slot inline
#pragma unroll
    for (int k = 0; k < 8; ++k) {
        const int i = t + k * BIN_T;
        if (i < nE) {
            const int pos = boff[myb[k]] + myrank[k];
            stage[pos] = (unsigned)myr[k];
            bkt_of[pos] = (unsigned short)myb[k];
        }
    }
    __syncthreads();

    for (int s = t; s < nE; s += BIN_T) {
        const int b = bkt_of[s];
        pairs[(size_t)b * CAP + gbase[b] + (s - boff[b])] = stage[s];
    }

    // block 0 tail: pack W1 -> B-fragments for mfma_f32_16x16x32_bf16.
    if (blockIdx.x == 0) {
        for (int idx = t; idx < 8 * 2 * 64 * 8; idx += BIN_T) {
            const int j = idx & 7;
            const int l = (idx >> 3) & 63;
            const int kk = (idx >> 9) & 1;
            const int d = idx >> 10;
            const int krow = (l >> 4) * 8 + kk * 32 + j;
            wpack[idx] = f2bf(W1[krow * D_HID + d * 16 + (l & 15)]);
        }
    }
}

// ---------------- per-bucket degrees -> dinv + xb = bf16(dinv*|x|) -----------

__global__ __launch_bounds__(AGG_T) void k_deg(const unsigned* __restrict__ pairs,
                                               const int* __restrict__ gcur,
                                               const float* __restrict__ x,
                                               float* __restrict__ dinv,
                                               unsigned short* __restrict__ xb) {
    __shared__ int ncnt[BKT_NODES];
    const int b = blockIdx.x, t = threadIdx.x;
    const int base = b << BKT_SHIFT;
    const int nNodes = min(BKT_NODES, N_NODES - base);
    const int nE = gcur[b];
    const unsigned* bp = pairs + (size_t)b * CAP;

    if (t < BKT_NODES) ncnt[t] = 0;
    __syncthreads();
    for (int i = t; i < nE; i += AGG_T) atomicAdd(&ncnt[P_DST(bp[i])], 1);
    __syncthreads();

    if (t < nNodes) dinv[base + t] = rsqrtf((float)ncnt[t] + 1.0f);

    for (int i = t; i < nNodes * 16; i += AGG_T) {
        const int nl = i >> 4;
        const int q = i & 15;
        const float di = rsqrtf((float)ncnt[nl] + 1.0f);
        const float4 v = ((const float4*)(x + (size_t)(base + nl) * D_IN))[q];
        ushort4 o4;
        o4.x = f2bf(di * fabsf(v.x));
        o4.y = f2bf(di * fabsf(v.y));
        o4.z = f2bf(di * fabsf(v.z));
        o4.w = f2bf(di * fabsf(v.w));
        *(ushort4*)(xb + (size_t)(base + nl) * D_IN + q * 4) = o4;
    }
}

// ---------------- layer-1 aggregate: LDS int fixed-point scatter-add ---------
// acc[256][65] int (pad 65). atomicAdd(int) on LDS = native ds_add_u32
// (R16-R18 saga: float LDS atomics -- plain AND unsafe -- are CAS loops).
// R18 config (256-node buckets, 4-deep stride-512 @ 1024T) + predicated
// 4-deep TAIL (R21 post-mortem: serial tail was the hidden cost of deeper
// unrolls / smaller buckets).

#define ATOM8(dst_, v_)                                                         \
    do {                                                                        \
        int* a_ = acc + (dst_) * 65 + dc * 8;                                   \
        atomicAdd(a_ + 0, (int)(bfu((unsigned short)((v_).x & 0xFFFF)) * SCALE_L1)); \
        atomicAdd(a_ + 1, (int)(bfu((unsigned short)((v_).x >> 16)) * SCALE_L1));    \
        atomicAdd(a_ + 2, (int)(bfu((unsigned short)((v_).y & 0xFFFF)) * SCALE_L1)); \
        atomicAdd(a_ + 3, (int)(bfu((unsigned short)((v_).y >> 16)) * SCALE_L1));    \
        atomicAdd(a_ + 4, (int)(bfu((unsigned short)((v_).z & 0xFFFF)) * SCALE_L1)); \
        atomicAdd(a_ + 5, (int)(bfu((unsigned short)((v_).z >> 16)) * SCALE_L1));    \
        atomicAdd(a_ + 6, (int)(bfu((unsigned short)((v_).w & 0xFFFF)) * SCALE_L1)); \
        atomicAdd(a_ + 7, (int)(bfu((unsigned short)((v_).w >> 16)) * SCALE_L1));    \
    } while (0)

__global__ __launch_bounds__(AGG_T) void k_aggL1(const unsigned* __restrict__ pairs,
                                                 const int* __restrict__ gcur,
                                                 const unsigned short* __restrict__ xb,
                                                 unsigned short* __restrict__ aggb) {
    __shared__ int acc[BKT_NODES * 65];  // 66.56 KB
    const int b = blockIdx.x, t = threadIdx.x;
    const int base = b << BKT_SHIFT;
    const int nNodes = min(BKT_NODES, N_NODES - base);
    const int nE = gcur[b];
    const unsigned* bp = pairs + (size_t)b * CAP;

    for (int i = t; i < BKT_NODES * 65; i += AGG_T) acc[i] = 0;
    __syncthreads();

    const int slot = t >> 3;   // 0..127 edge slots
    const int dc = t & 7;      // dims 8*dc..8*dc+7
    int i = slot;
    for (; i + 384 < nE; i += 512) {  // 4 gathers in flight per lane
        const unsigned u0 = bp[i];
        const unsigned u1 = bp[i + 128];
        const unsigned u2 = bp[i + 256];
        const unsigned u3 = bp[i + 384];
        const uint4 v0 = ((const uint4*)(xb + (size_t)P_ROW(u0) * D_IN))[dc];
        const uint4 v1 = ((const uint4*)(xb + (size_t)P_ROW(u1) * D_IN))[dc];
        const uint4 v2 = ((const uint4*)(xb + (size_t)P_ROW(u2) * D_IN))[dc];
        const uint4 v3 = ((const uint4*)(xb + (size_t)P_ROW(u3) * D_IN))[dc];
        ATOM8(P_DST(u0), v0);
        ATOM8(P_DST(u1), v1);
        ATOM8(P_DST(u2), v2);
        ATOM8(P_DST(u3), v3);
    }
    // predicated 4-deep tail: keep all remaining gathers in flight
    if (i < nE) {
        const bool h1 = (i + 128 < nE);
        const bool h2 = (i + 256 < nE);
        const bool h3 = (i + 384 < nE);
        const unsigned u0 = bp[i];
        const unsigned u1 = h1 ? bp[i + 128] : u0;
        const unsigned u2 = h2 ? bp[i + 256] : u0;
        const unsigned u3 = h3 ? bp[i + 384] : u0;
        const uint4 v0 = ((const uint4*)(xb + (size_t)P_ROW(u0) * D_IN))[dc];
        const uint4 v1 = ((const uint4*)(xb + (size_t)P_ROW(u1) * D_IN))[dc];
        const uint4 v2 = ((const uint4*)(xb + (size_t)P_ROW(u2) * D_IN))[dc];
        const uint4 v3 = ((const uint4*)(xb + (size_t)P_ROW(u3) * D_IN))[dc];
        ATOM8(P_DST(u0), v0);
        if (h1) ATOM8(P_DST(u1), v1);
        if (h2) ATOM8(P_DST(u2), v2);
        if (h3) ATOM8(P_DST(u3), v3);
    }
    __syncthreads();

    // add self-loop (float) and pack to bf16 aggb; thread covers 16 dims
    for (int j = t; j < nNodes * 4; j += AGG_T) {
        const int nl = j >> 2;
        const int q = j & 3;          // dims q*16 .. q*16+15
        const uint4 s0 = ((const uint4*)(xb + (size_t)(base + nl) * D_IN))[q * 2];
        const uint4 s1 = ((const uint4*)(xb + (size_t)(base + nl) * D_IN))[q * 2 + 1];
        const int* ar = acc + nl * 65 + q * 16;
        uint4 w0, w1;
        w0.x = (unsigned)f2bf((float)ar[0] * INV_SCALE_L1 + bfu((unsigned short)(s0.x & 0xFFFF))) |
               ((unsigned)f2bf((float)ar[1] * INV_SCALE_L1 + bfu((unsigned short)(s0.x >> 16))) << 16);
        w0.y = (unsigned)f2bf((float)ar[2] * INV_SCALE_L1 + bfu((unsigned short)(s0.y & 0xFFFF))) |
               ((unsigned)f2bf((float)ar[3] * INV_SCALE_L1 + bfu((unsigned short)(s0.y >> 16))) << 16);
        w0.z = (unsigned)f2bf((float)ar[4] * INV_SCALE_L1 + bfu((unsigned short)(s0.z & 0xFFFF))) |
               ((unsigned)f2bf((float)ar[5] * INV_SCALE_L1 + bfu((unsigned short)(s0.z >> 16))) << 16);
        w0.w = (unsigned)f2bf((float)ar[6] * INV_SCALE_L1 + bfu((unsigned short)(s0.w & 0xFFFF))) |
               ((unsigned)f2bf((float)ar[7] * INV_SCALE_L1 + bfu((unsigned short)(s0.w >> 16))) << 16);
        w1.x = (unsigned)f2bf((float)ar[8] * INV_SCALE_L1 + bfu((unsigned short)(s1.x & 0xFFFF))) |
               ((unsigned)f2bf((float)ar[9] * INV_SCALE_L1 + bfu((unsigned short)(s1.x >> 16))) << 16);
        w1.y = (unsigned)f2bf((float)ar[10] * INV_SCALE_L1 + bfu((unsigned short)(s1.y & 0xFFFF))) |
               ((unsigned)f2bf((float)ar[11] * INV_SCALE_L1 + bfu((unsigned short)(s1.y >> 16))) << 16);
        w1.z = (unsigned)f2bf((float)ar[12] * INV_SCALE_L1 + bfu((unsigned short)(s1.z & 0xFFFF))) |
               ((unsigned)f2bf((float)ar[13] * INV_SCALE_L1 + bfu((unsigned short)(s1.z >> 16))) << 16);
        w1.w = (unsigned)f2bf((float)ar[14] * INV_SCALE_L1 + bfu((unsigned short)(s1.w & 0xFFFF))) |
               ((unsigned)f2bf((float)ar[15] * INV_SCALE_L1 + bfu((unsigned short)(s1.w >> 16))) << 16);
        uint4* dst = (uint4*)(aggb + (size_t)(base + nl) * D_IN + q * 16);
        dst[0] = w0;
        dst[1] = w1;
    }
}

// ---------------- MFMA GEMM: g = aggb @ W1; h=relu(di*g+b1); z=di*(h.W2) ----

#define EPI(di_, accv, reg, p_)                                            \
    do {                                                                   \
        float h_ = fmaxf(fmaf((di_), (accv)[reg], b1v), 0.0f);             \
        (p_) = fmaf(h_, w2v, (p_));                                        \
    } while (0)

#define RSTORE(p_, di_, nn_)                                               \
    do {                                                                   \
        float sv = (p_);                                                   \
        sv += __shfl_xor(sv, 1, 64);                                       \
        sv += __shfl_xor(sv, 2, 64);                                       \
        sv += __shfl_xor(sv, 4, 64);                                       \
        sv += __shfl_xor(sv, 8, 64);                                       \
        if ((lane & 15) == 0 && (nn_) < N_NODES) z[(nn_)] = (di_) * sv;    \
    } while (0)

__global__ __launch_bounds__(GM_T) void k_gemm(const unsigned short* __restrict__ aggb,
                                               const unsigned short* __restrict__ wpack,
                                               const float* __restrict__ dinv,
                                               const float* __restrict__ b1,
                                               const float* __restrict__ W2,
                                               float* __restrict__ z) {
    const int t = threadIdx.x;
    const int lane = t & 63;
    const int w = t >> 6;                  // wave 0..3
    const int kg = lane >> 4;              // 0..3
    const int n0 = blockIdx.x * GM_NODES;
    const int nbase0 = n0 + (2 * w) * 16;
    const int nbase1 = nbase0 + 16;

    const bf16x8 a00 = *(const bf16x8*)(aggb + (size_t)(nbase0 + (lane & 15)) * D_IN + kg * 8);
    const bf16x8 a01 = *(const bf16x8*)(aggb + (size_t)(nbase0 + (lane & 15)) * D_IN + kg * 8 + 32);
    const bf16x8 a10 = *(const bf16x8*)(aggb + (size_t)(nbase1 + (lane & 15)) * D_IN + kg * 8);
    const bf16x8 a11 = *(const bf16x8*)(aggb + (size_t)(nbase1 + (lane & 15)) * D_IN + kg * 8 + 32);

    const float di00 = dinv[nbase0 + kg * 4 + 0];
    const float di01 = dinv[nbase0 + kg * 4 + 1];
    const float di02 = dinv[nbase0 + kg * 4 + 2];
    const float di03 = dinv[nbase0 + kg * 4 + 3];
    const float di10 = dinv[nbase1 + kg * 4 + 0];
    const float di11 = dinv[nbase1 + kg * 4 + 1];
    const float di12 = dinv[nbase1 + kg * 4 + 2];
    const float di13 = dinv[nbase1 + kg * 4 + 3];

    float p00 = 0, p01 = 0, p02 = 0, p03 = 0;
    float p10 = 0, p11 = 0, p12 = 0, p13 = 0;

#pragma unroll
    for (int d = 0; d < 8; ++d) {
        const bf16x8 wb0 = *(const bf16x8*)(wpack + ((size_t)(d * 2 + 0) * 64 + lane) * 8);
        const bf16x8 wb1 = *(const bf16x8*)(wpack + ((size_t)(d * 2 + 1) * 64 + lane) * 8);
        f32x4 acc0 = {0.0f, 0.0f, 0.0f, 0.0f};
        acc0 = __builtin_amdgcn_mfma_f32_16x16x32_bf16(a00, wb0, acc0, 0, 0, 0);
        acc0 = __builtin_amdgcn_mfma_f32_16x16x32_bf16(a01, wb1, acc0, 0, 0, 0);
        f32x4 acc1 = {0.0f, 0.0f, 0.0f, 0.0f};
        acc1 = __builtin_amdgcn_mfma_f32_16x16x32_bf16(a10, wb0, acc1, 0, 0, 0);
        acc1 = __builtin_amdgcn_mfma_f32_16x16x32_bf16(a11, wb1, acc1, 0, 0, 0);

        const int cold = d * 16 + (lane & 15);
        const float b1v = b1[cold];
        const float w2v = W2[cold];
        EPI(di00, acc0, 0, p00);
        EPI(di01, acc0, 1, p01);
        EPI(di02, acc0, 2, p02);
        EPI(di03, acc0, 3, p03);
        EPI(di10, acc1, 0, p10);
        EPI(di11, acc1, 1, p11);
        EPI(di12, acc1, 2, p12);
        EPI(di13, acc1, 3, p13);
    }

    RSTORE(p00, di00, nbase0 + kg * 4 + 0);
    RSTORE(p01, di01, nbase0 + kg * 4 + 1);
    RSTORE(p02, di02, nbase0 + kg * 4 + 2);
    RSTORE(p03, di03, nbase0 + kg * 4 + 3);
    RSTORE(p10, di10, nbase1 + kg * 4 + 0);
    RSTORE(p11, di11, nbase1 + kg * 4 + 1);
    RSTORE(p12, di12, nbase1 + kg * 4 + 2);
    RSTORE(p13, di13, nbase1 + kg * 4 + 3);
}

// ---------------- layer-2 aggregate + final: LDS int scatter-add -------------

__global__ __launch_bounds__(AGG_T) void k_outL2(const unsigned* __restrict__ pairs,
                                                 const int* __restrict__ gcur,
                                                 const float* __restrict__ z,
                                                 const float* __restrict__ dinv,
                                                 const float* __restrict__ b2,
                                                 float* __restrict__ out) {
    __shared__ int acc2[BKT_NODES];
    const int b = blockIdx.x, t = threadIdx.x;
    const int base = b << BKT_SHIFT;
    const int nNodes = min(BKT_NODES, N_NODES - base);
    const int nE = gcur[b];
    const unsigned* bp = pairs + (size_t)b * CAP;

    if (t < BKT_NODES) acc2[t] = 0;
    __syncthreads();

    int i = t;
    for (; i + AGG_T < nE; i += 2 * AGG_T) {  // 2 z-gathers in flight
        const unsigned u0 = bp[i];
        const unsigned u1 = bp[i + AGG_T];
        const float z0 = z[P_ROW(u0)];
        const float z1 = z[P_ROW(u1)];
        atomicAdd(&acc2[P_DST(u0)], (int)(z0 * SCALE_L2));
        atomicAdd(&acc2[P_DST(u1)], (int)(z1 * SCALE_L2));
    }
    if (i < nE) {
        const unsigned u = bp[i];
        atomicAdd(&acc2[P_DST(u)], (int)(z[P_ROW(u)] * SCALE_L2));
    }
    __syncthreads();

    if (t < nNodes) {
        float s = (float)acc2[t] * INV_SCALE_L2 + z[base + t];
        float v = fmaf(dinv[base + t], s, b2[0]);
        v = fmaxf(v, 0.0f);
        out[base + t] = 1.0f / (1.0f + expf(-v));
    }
}

extern "C" void kernel_launch(void* const* d_in, const int* in_sizes, int n_in,
                              void* d_out, int out_size, void* d_ws, size_t ws_size,
                              hipStream_t stream) {
    const float* x  = (const float*)d_in[0];
    const int* ei   = (const int*)d_in[1];
    const float* W1 = (const float*)d_in[2];
    const float* b1 = (const float*)d_in[3];
    const float* W2 = (const float*)d_in[4];
    const float* b2 = (const float*)d_in[5];
    float* out = (float*)d_out;

    const int* row = ei;
    const int* col = ei + N_EDGES;

    // workspace layout
    char* p = (char*)d_ws;
    float* dinv           = (float*)p;          p += sizeof(float) * N_NODES;
    unsigned short* xb    = (unsigned short*)p; p += sizeof(unsigned short) * (size_t)N_NODES * D_IN;
    unsigned short* aggb  = (unsigned short*)p; p += sizeof(unsigned short) * ((size_t)N_NODES + 128) * D_IN;
    float* z              = (float*)p;          p += sizeof(float) * (N_NODES + 128);
    int* gcur             = (int*)p;            p += sizeof(int) * NB;
    p = (char*)(((size_t)p + 15) & ~(size_t)15);
    unsigned short* wpack = (unsigned short*)p; p += sizeof(unsigned short) * 8192;
    p = (char*)(((size_t)p + 15) & ~(size_t)15);
    unsigned* pairs       = (unsigned*)p;       p += sizeof(unsigned) * (size_t)NB * CAP;

    hipMemsetAsync(gcur, 0, sizeof(int) * NB, stream);
    k_bin<<<(N_EDGES + CHUNK - 1) / CHUNK, BIN_T, 0, stream>>>(row, col, W1, gcur, pairs, wpack);
    k_deg<<<NB, AGG_T, 0, stream>>>(pairs, gcur, x, dinv, xb);
    k_aggL1<<<NB, AGG_T, 0, stream>>>(pairs, gcur, xb, aggb);
    k_gemm<<<GM_NBLK, GM_T, 0, stream>>>(aggb, wpack, dinv, b1, W2, z);
    k_outL2<<<NB, AGG_T, 0, stream>>>(pairs, gcur, z, dinv, b2, out);
}